// Round 9
// baseline (2000.728 us; speedup 1.0000x reference)
//
#include <hip/hip_runtime.h>

#define NN 100000
#define NE 3200000
#define DIN 512
#define DHID 256
#define DOUT 64
#define KPROP 10
#define NPART 8
#define PSZ 12500   // nodes per dst-partition (8 x 12500 = 100000)
#define NBLK 782    // prop blocks per feature-slice: 782*128 >= NN

typedef _Float16 f16;
typedef _Float16 f16x8 __attribute__((ext_vector_type(8)));
typedef _Float16 f16x4 __attribute__((ext_vector_type(4)));
typedef float f32x4 __attribute__((ext_vector_type(4)));

// ---------------- edge-index layout probe (wave-parallel) ----------------
__global__ void detect_i64(const int* __restrict__ ei, int* __restrict__ flag) {
  int lane = threadIdx.x;
  int ok = 1;
  for (int i = lane; i < 512; i += 64)
    if (ei[2 * i + 1] != 0) ok = 0;
  ok = __all(ok);
  if (lane == 0) *flag = ok;
}

__global__ void zero_cnt(int* __restrict__ cnt) {
  int g = blockIdx.x * blockDim.x + threadIdx.x;
  if (g < NN) cnt[g] = 0;
}

// ---------------- degree count: XCD-routed (r8 measured-best) ----------------
__global__ __launch_bounds__(256) void count_deg(
    const int* __restrict__ ei, const int* __restrict__ flag,
    int* __restrict__ cnt) {
  int p = blockIdx.x & 7;
  int chunk = blockIdx.x >> 3;
  int e0 = chunk * 1024 + threadIdx.x * 4;
  if (e0 >= NE) return;
  int is64 = *flag;
  int d0, d1, d2, d3;
  if (is64) {
    int4 a = *(const int4*)&ei[2 * (size_t)NE + 2 * (size_t)e0];
    int4 b = *(const int4*)&ei[2 * (size_t)NE + 2 * (size_t)e0 + 4];
    d0 = a.x; d1 = a.z; d2 = b.x; d3 = b.z;
  } else {
    int4 a = *(const int4*)&ei[(size_t)NE + e0];
    d0 = a.x; d1 = a.y; d2 = a.z; d3 = a.w;
  }
  int lo = p * PSZ, hi = lo + PSZ;
  if (d0 >= lo && d0 < hi) atomicAdd(&cnt[d0], 1);
  if (d1 >= lo && d1 < hi) atomicAdd(&cnt[d1], 1);
  if (d2 >= lo && d2 < hi) atomicAdd(&cnt[d2], 1);
  if (d3 >= lo && d3 < hi) atomicAdd(&cnt[d3], 1);
}

// ---------------- exclusive scan over cnt ----------------
__global__ void scan1(const int* __restrict__ cnt, int* __restrict__ rs,
                      int* __restrict__ bsum) {
  __shared__ int tmp[1024];
  int t = threadIdx.x;
  int g = blockIdx.x * 1024 + t;
  int v = (g < NN) ? cnt[g] : 0;
  tmp[t] = v;
  __syncthreads();
  for (int off = 1; off < 1024; off <<= 1) {
    int y = (t >= off) ? tmp[t - off] : 0;
    __syncthreads();
    tmp[t] += y;
    __syncthreads();
  }
  if (g < NN) rs[g] = tmp[t] - v;           // exclusive
  if (t == 1023) bsum[blockIdx.x] = tmp[t]; // block total
}

__global__ void scan2(int* __restrict__ bsum, int nb) {
  if (blockIdx.x == 0 && threadIdx.x == 0) {
    int s = 0;
    for (int i = 0; i < nb; i++) { int v = bsum[i]; bsum[i] = s; s += v; }
  }
}

__global__ void scan3_and_dis(int* __restrict__ rs, const int* __restrict__ bsum,
                              int* __restrict__ cursor, const int* __restrict__ cnt,
                              float* __restrict__ dis) {
  int g = blockIdx.x * blockDim.x + threadIdx.x;
  if (g < NN) {
    int v = rs[g] + bsum[g >> 10];
    rs[g] = v;
    cursor[g] = v;
    dis[g] = rsqrtf((float)(cnt[g] + 1)); // +1 self-loop
  }
}

// ---------------- CSR fill: XCD-routed {col, norm} records (r8 best) ------
__global__ __launch_bounds__(256) void fill_csr(
    const int* __restrict__ ei, const int* __restrict__ flag,
    const float* __restrict__ dis, int* __restrict__ cursor,
    int2* __restrict__ recs) {
  int p = blockIdx.x & 7;
  int chunk = blockIdx.x >> 3;
  int e0 = chunk * 1024 + threadIdx.x * 4;
  if (e0 >= NE) return;
  int is64 = *flag;
  int d[4];
  if (is64) {
    int4 a = *(const int4*)&ei[2 * (size_t)NE + 2 * (size_t)e0];
    int4 b = *(const int4*)&ei[2 * (size_t)NE + 2 * (size_t)e0 + 4];
    d[0] = a.x; d[1] = a.z; d[2] = b.x; d[3] = b.z;
  } else {
    int4 a = *(const int4*)&ei[(size_t)NE + e0];
    d[0] = a.x; d[1] = a.y; d[2] = a.z; d[3] = a.w;
  }
  int lo = p * PSZ, hi = lo + PSZ;
  #pragma unroll
  for (int j = 0; j < 4; j++) {
    if (d[j] >= lo && d[j] < hi) {
      int s = is64 ? ei[2 * (size_t)(e0 + j)] : ei[e0 + j];
      int pos = atomicAdd(&cursor[d[j]], 1);
      recs[pos] = make_int2(s, __float_as_int(dis[s] * dis[d[j]]));
    }
  }
}

// ---------------- weight transpose + fp16 convert ----------------
__global__ void cvt_weights(const float* __restrict__ W1, const float* __restrict__ W2,
                            f16* __restrict__ W1t, f16* __restrict__ W2t) {
  int g = blockIdx.x * 256 + threadIdx.x;
  if (g < DIN * DHID) {
    int k = g >> 8, n = g & 255;
    W1t[(size_t)n * DIN + k] = (f16)W1[g];
  }
  if (g < DHID * DOUT) {
    int k = g >> 6, n = g & 63;
    W2t[(size_t)n * DHID + k] = (f16)W2[g];
  }
}

// ---------------- fused MLP via f16 MFMA (pipelined, union LDS) ----------
// Epilogue writes column-major slices: h_cm/z_cm[fb][node][16], fb = nt.
__global__ __launch_bounds__(256) void mlp_mfma(
    const float* __restrict__ x, const f16* __restrict__ W1t,
    const float* __restrict__ b1, const f16* __restrict__ W2t,
    const float* __restrict__ b2, const float* __restrict__ temp,
    f16* __restrict__ hcm, f16* __restrict__ zcm)
{
  __shared__ __align__(16) char smraw[2 * 64 * 136 * 2]; // 34816 B
  f16* xsb = (f16*)smraw;          // xs[buf][row][136]
  f16* h1s = (f16*)smraw;          // h1s[row][264] (aliases xs; disjoint lifetime)
  int t = threadIdx.x;
  int lane = t & 63;
  int w = t >> 6;
  int n0 = blockIdx.x * 64;
  int r15 = lane & 15;
  int g4 = lane >> 4;
  int nbase = w * 64;
  int srow = t >> 5, sc4 = t & 31;

  f32x4 acc[4][4];
  #pragma unroll
  for (int nt = 0; nt < 4; nt++) {
    float bv = b1[nbase + nt * 16 + r15];
    #pragma unroll
    for (int mt = 0; mt < 4; mt++) acc[mt][nt] = (f32x4){bv, bv, bv, bv};
  }

  float4 ld[8];
  #pragma unroll
  for (int it = 0; it < 8; it++) {
    int row = srow + it * 8;
    int gr = n0 + row;
    ld[it] = (gr < NN) ? *(const float4*)&x[(size_t)gr * DIN + sc4 * 4]
                       : make_float4(0.f, 0.f, 0.f, 0.f);
  }
  #pragma unroll
  for (int it = 0; it < 8; it++) {
    int row = srow + it * 8;
    f16x4 hv = { (f16)ld[it].x, (f16)ld[it].y, (f16)ld[it].z, (f16)ld[it].w };
    *(f16x4*)&xsb[row * 136 + sc4 * 4] = hv;
  }
  __syncthreads();

  for (int c = 0; c < 4; c++) {
    int cur = c & 1;
    if (c < 3) {
      #pragma unroll
      for (int it = 0; it < 8; it++) {
        int row = srow + it * 8;
        int gr = n0 + row;
        ld[it] = (gr < NN)
            ? *(const float4*)&x[(size_t)gr * DIN + (c + 1) * 128 + sc4 * 4]
            : make_float4(0.f, 0.f, 0.f, 0.f);
      }
    }
    int k0 = c * 128;
    const f16* xs = xsb + cur * 8704;
    #pragma unroll
    for (int ks = 0; ks < 4; ks++) {
      int kk = ks * 32 + g4 * 8;
      f16x8 a[4], b[4];
      #pragma unroll
      for (int mt = 0; mt < 4; mt++)
        a[mt] = *(const f16x8*)&xs[(mt * 16 + r15) * 136 + kk];
      #pragma unroll
      for (int nt = 0; nt < 4; nt++)
        b[nt] = *(const f16x8*)&W1t[(size_t)(nbase + nt * 16 + r15) * DIN + k0 + kk];
      #pragma unroll
      for (int mt = 0; mt < 4; mt++)
        #pragma unroll
        for (int nt = 0; nt < 4; nt++)
          acc[mt][nt] = __builtin_amdgcn_mfma_f32_16x16x32_f16(a[mt], b[nt], acc[mt][nt], 0, 0, 0);
    }
    if (c < 3) {
      #pragma unroll
      for (int it = 0; it < 8; it++) {
        int row = srow + it * 8;
        f16x4 hv = { (f16)ld[it].x, (f16)ld[it].y, (f16)ld[it].z, (f16)ld[it].w };
        *(f16x4*)&xsb[(cur ^ 1) * 8704 + row * 136 + sc4 * 4] = hv;
      }
    }
    __syncthreads();
  }

  #pragma unroll
  for (int mt = 0; mt < 4; mt++)
    #pragma unroll
    for (int nt = 0; nt < 4; nt++)
      #pragma unroll
      for (int r = 0; r < 4; r++) {
        float v = fmaxf(acc[mt][nt][r], 0.f);
        h1s[(mt * 16 + g4 * 4 + r) * 264 + nbase + nt * 16 + r15] = (f16)v;
      }
  __syncthreads();

  f32x4 acc2[4];
  #pragma unroll
  for (int nt = 0; nt < 4; nt++) {
    float bv = b2[nt * 16 + r15];
    acc2[nt] = (f32x4){bv, bv, bv, bv};
  }
  #pragma unroll
  for (int ks = 0; ks < 8; ks++) {
    int kk = ks * 32 + g4 * 8;
    f16x8 a2 = *(const f16x8*)&h1s[(w * 16 + r15) * 264 + kk];
    #pragma unroll
    for (int nt = 0; nt < 4; nt++) {
      f16x8 bf = *(const f16x8*)&W2t[(size_t)(nt * 16 + r15) * DHID + kk];
      acc2[nt] = __builtin_amdgcn_mfma_f32_16x16x32_f16(a2, bf, acc2[nt], 0, 0, 0);
    }
  }
  float tK = temp[KPROP];
  #pragma unroll
  for (int nt = 0; nt < 4; nt++)
    #pragma unroll
    for (int r = 0; r < 4; r++) {
      int node = n0 + w * 16 + g4 * 4 + r;
      if (node < NN) {
        size_t o = (size_t)nt * NN * 16 + (size_t)node * 16 + r15;
        float v = acc2[nt][r];
        hcm[o] = (f16)v;
        zcm[o] = (f16)(tK * v);
      }
    }
}

// ---------------- feature-chunked Horner prop: z_new = temp[k]*h + A_hat z --
// Column-major slices [fb][NN][16] f16; one slice = 3.2MB < 4MB per-XCD L2,
// so gathers are L2-resident while the grid works through slice fb
// (fb = blockIdx.x/NBLK, x-major dispatch sequences the slices). 2 threads
// per dst node, each owns 8 features -> no cross-lane combine; the pair's two
// 16B gathers share one 64B sector. Prop was L3-BW-bound at ~7TB/s (r8
// accounting: 474MB/step in 65us); same bytes from L2 should halve step time.
__global__ __launch_bounds__(256) void prop_fb(
    const f16* __restrict__ z, f16* __restrict__ zn, const f16* __restrict__ hcm,
    float* __restrict__ out, const int* __restrict__ rs, const int* __restrict__ cnt,
    const int2* __restrict__ recs, const float* __restrict__ dis,
    const float* __restrict__ temp, int kidx, int final_step)
{
  int fb = blockIdx.x / NBLK;
  int nb = blockIdx.x - fb * NBLK;
  int t = threadIdx.x;
  int dst = nb * 128 + (t >> 1);
  if (dst >= NN) return;
  int p = t & 1;                        // feature half: p*8 .. p*8+7
  const f16* zs = z + (size_t)fb * NN * 16 + p * 8;

  float acc[8];
  #pragma unroll
  for (int f = 0; f < 8; f++) acc[f] = 0.f;

  int beg = rs[dst], n = cnt[dst];
  const int2* rp = recs + beg;
  int e = 0;
  for (; e + 4 <= n; e += 4) {
    int2 r0 = rp[e + 0], r1 = rp[e + 1], r2 = rp[e + 2], r3 = rp[e + 3];
    f16x8 g0 = *(const f16x8*)&zs[(size_t)r0.x * 16];
    f16x8 g1 = *(const f16x8*)&zs[(size_t)r1.x * 16];
    f16x8 g2 = *(const f16x8*)&zs[(size_t)r2.x * 16];
    f16x8 g3 = *(const f16x8*)&zs[(size_t)r3.x * 16];
    float w0 = __int_as_float(r0.y), w1 = __int_as_float(r1.y);
    float w2 = __int_as_float(r2.y), w3 = __int_as_float(r3.y);
    #pragma unroll
    for (int f = 0; f < 8; f++) acc[f] = fmaf(w0, (float)g0[f], acc[f]);
    #pragma unroll
    for (int f = 0; f < 8; f++) acc[f] = fmaf(w1, (float)g1[f], acc[f]);
    #pragma unroll
    for (int f = 0; f < 8; f++) acc[f] = fmaf(w2, (float)g2[f], acc[f]);
    #pragma unroll
    for (int f = 0; f < 8; f++) acc[f] = fmaf(w3, (float)g3[f], acc[f]);
  }
  for (; e < n; ++e) {
    int2 r0 = rp[e];
    f16x8 g0 = *(const f16x8*)&zs[(size_t)r0.x * 16];
    float w0 = __int_as_float(r0.y);
    #pragma unroll
    for (int f = 0; f < 8; f++) acc[f] = fmaf(w0, (float)g0[f], acc[f]);
  }

  float dd = dis[dst];
  float dd2 = dd * dd;                  // self-loop norm
  float gk = temp[kidx];
  f16x8 zf = *(const f16x8*)&zs[(size_t)dst * 16];
  f16x8 hf = *(const f16x8*)&hcm[(size_t)fb * NN * 16 + (size_t)dst * 16 + p * 8];
  #pragma unroll
  for (int f = 0; f < 8; f++)
    acc[f] += dd2 * (float)zf[f] + gk * (float)hf[f];

  if (final_step) {
    float4 o0 = { acc[0], acc[1], acc[2], acc[3] };
    float4 o1 = { acc[4], acc[5], acc[6], acc[7] };
    size_t o = (size_t)dst * DOUT + fb * 16 + p * 8;
    *(float4*)&out[o] = o0;
    *(float4*)&out[o + 4] = o1;
  } else {
    f16x8 ov;
    #pragma unroll
    for (int f = 0; f < 8; f++) ov[f] = (f16)acc[f];
    *(f16x8*)&zn[(size_t)fb * NN * 16 + (size_t)dst * 16 + p * 8] = ov;
  }
}

// ---------------- launch ----------------
extern "C" void kernel_launch(void* const* d_in, const int* in_sizes, int n_in,
                              void* d_out, int out_size, void* d_ws, size_t ws_size,
                              hipStream_t stream) {
  const float* x    = (const float*)d_in[0];
  const int*   ei   = (const int*)d_in[1];
  const float* W1   = (const float*)d_in[2];
  const float* b1   = (const float*)d_in[3];
  const float* W2   = (const float*)d_in[4];
  const float* b2   = (const float*)d_in[5];
  const float* temp = (const float*)d_in[6];
  float* out = (float*)d_out;

  char* wsb = (char*)d_ws;
  size_t off = 0;
  auto carve = [&](size_t bytes) -> void* {
    void* p = wsb + off;
    off = (off + bytes + 255) & ~(size_t)255;
    return p;
  };
  int*   cnt    = (int*)carve((size_t)NN * 4);
  int*   rs     = (int*)carve((size_t)NN * 4);
  int*   cursor = (int*)carve((size_t)NN * 4);
  int*   bsum   = (int*)carve(128 * 4);
  int*   flag   = (int*)carve(256);
  float* dis    = (float*)carve((size_t)NN * 4);
  int2*  recs   = (int2*)carve((size_t)NE * 8);  // 25.6 MB
  f16*   W1t    = (f16*)carve((size_t)DHID * DIN * 2);
  f16*   W2t    = (f16*)carve((size_t)DOUT * DHID * 2);
  f16*   h_cm   = (f16*)carve((size_t)NN * DOUT * 2);
  f16*   z_a    = (f16*)carve((size_t)NN * DOUT * 2);
  f16*   z_b    = (f16*)carve((size_t)NN * DOUT * 2);
  if (off > ws_size) return; // ~67 MB needed

  int nchunks = NE / 1024;  // 3125 (exact)

  detect_i64<<<1, 64, 0, stream>>>(ei, flag);
  zero_cnt<<<(NN + 255) / 256, 256, 0, stream>>>(cnt);
  count_deg<<<nchunks * NPART, 256, 0, stream>>>(ei, flag, cnt);
  scan1<<<(NN + 1023) / 1024, 1024, 0, stream>>>(cnt, rs, bsum);
  scan2<<<1, 64, 0, stream>>>(bsum, (NN + 1023) / 1024);
  scan3_and_dis<<<(NN + 255) / 256, 256, 0, stream>>>(rs, bsum, cursor, cnt, dis);
  fill_csr<<<nchunks * NPART, 256, 0, stream>>>(ei, flag, dis, cursor, recs);

  cvt_weights<<<(DIN * DHID + 255) / 256, 256, 0, stream>>>(W1, W2, W1t, W2t);
  mlp_mfma<<<(NN + 63) / 64, 256, 0, stream>>>(x, W1t, b1, W2t, b2, temp, h_cm, z_a);

  const f16* zc = z_a;
  f16* zn = z_b;
  for (int k = KPROP - 1; k >= 0; k--) {
    prop_fb<<<NBLK * 4, 256, 0, stream>>>(zc, zn, h_cm, out, rs, cnt, recs,
                                          dis, temp, k, k == 0);
    const f16* t2 = zn;
    zn = (f16*)zc;
    zc = t2;
  }
}

// Round 11
// 1080.031 us; speedup vs baseline: 1.8525x; 1.8525x over previous
//
#include <hip/hip_runtime.h>

#define NN 100000
#define NE 3200000
#define DIN 512
#define DHID 256
#define DOUT 64
#define KPROP 10
#define NPART 8
#define PSZ 12500   // nodes per dst-partition (8 x 12500 = 100000)

typedef _Float16 f16;
typedef _Float16 f16x8 __attribute__((ext_vector_type(8)));
typedef _Float16 f16x4 __attribute__((ext_vector_type(4)));
typedef float f32x4 __attribute__((ext_vector_type(4)));
typedef int i32x4 __attribute__((ext_vector_type(4)));   // NT-load-compatible
typedef int i32x2 __attribute__((ext_vector_type(2)));

// ---------------- edge-index layout probe (wave-parallel) ----------------
__global__ void detect_i64(const int* __restrict__ ei, int* __restrict__ flag) {
  int lane = threadIdx.x;
  int ok = 1;
  for (int i = lane; i < 512; i += 64)
    if (ei[2 * i + 1] != 0) ok = 0;
  ok = __all(ok);
  if (lane == 0) *flag = ok;
}

__global__ void zero_cnt(int* __restrict__ cnt) {
  int g = blockIdx.x * blockDim.x + threadIdx.x;
  if (g < NN) cnt[g] = 0;
}

// ---------------- degree count: XCD-routed + NT reads ----------------
// Routing keeps each cnt line's atomics on one XCD. NT loads keep the 8x ei
// re-stream from evicting hot lines out of that XCD's 4MB L2 (r8 lesson:
// routed re-reads polluted L2 and kept write amplification at 200MB).
__global__ __launch_bounds__(256) void count_deg(
    const int* __restrict__ ei, const int* __restrict__ flag,
    int* __restrict__ cnt) {
  int p = blockIdx.x & 7;
  int chunk = blockIdx.x >> 3;
  int e0 = chunk * 1024 + threadIdx.x * 4;
  if (e0 >= NE) return;
  int is64 = *flag;
  int d0, d1, d2, d3;
  if (is64) {
    i32x4 a = __builtin_nontemporal_load((const i32x4*)&ei[2 * (size_t)NE + 2 * (size_t)e0]);
    i32x4 b = __builtin_nontemporal_load((const i32x4*)&ei[2 * (size_t)NE + 2 * (size_t)e0 + 4]);
    d0 = a[0]; d1 = a[2]; d2 = b[0]; d3 = b[2];
  } else {
    i32x4 a = __builtin_nontemporal_load((const i32x4*)&ei[(size_t)NE + e0]);
    d0 = a[0]; d1 = a[1]; d2 = a[2]; d3 = a[3];
  }
  int lo = p * PSZ, hi = lo + PSZ;
  if (d0 >= lo && d0 < hi) atomicAdd(&cnt[d0], 1);
  if (d1 >= lo && d1 < hi) atomicAdd(&cnt[d1], 1);
  if (d2 >= lo && d2 < hi) atomicAdd(&cnt[d2], 1);
  if (d3 >= lo && d3 < hi) atomicAdd(&cnt[d3], 1);
}

// ---------------- exclusive scan over cnt ----------------
__global__ void scan1(const int* __restrict__ cnt, int* __restrict__ rs,
                      int* __restrict__ bsum) {
  __shared__ int tmp[1024];
  int t = threadIdx.x;
  int g = blockIdx.x * 1024 + t;
  int v = (g < NN) ? cnt[g] : 0;
  tmp[t] = v;
  __syncthreads();
  for (int off = 1; off < 1024; off <<= 1) {
    int y = (t >= off) ? tmp[t - off] : 0;
    __syncthreads();
    tmp[t] += y;
    __syncthreads();
  }
  if (g < NN) rs[g] = tmp[t] - v;           // exclusive
  if (t == 1023) bsum[blockIdx.x] = tmp[t]; // block total
}

__global__ void scan2(int* __restrict__ bsum, int nb) {
  if (blockIdx.x == 0 && threadIdx.x == 0) {
    int s = 0;
    for (int i = 0; i < nb; i++) { int v = bsum[i]; bsum[i] = s; s += v; }
  }
}

__global__ void scan3_and_dis(int* __restrict__ rs, const int* __restrict__ bsum,
                              int* __restrict__ cursor, const int* __restrict__ cnt,
                              float* __restrict__ dis) {
  int g = blockIdx.x * blockDim.x + threadIdx.x;
  if (g < NN) {
    int v = rs[g] + bsum[g >> 10];
    rs[g] = v;
    cursor[g] = v;
    dis[g] = rsqrtf((float)(cnt[g] + 1)); // +1 self-loop
  }
}

// ---------------- CSR fill: XCD-routed {col, norm} records + NT reads -----
__global__ __launch_bounds__(256) void fill_csr(
    const int* __restrict__ ei, const int* __restrict__ flag,
    const float* __restrict__ dis, int* __restrict__ cursor,
    int2* __restrict__ recs) {
  int p = blockIdx.x & 7;
  int chunk = blockIdx.x >> 3;
  int e0 = chunk * 1024 + threadIdx.x * 4;
  if (e0 >= NE) return;
  int is64 = *flag;
  int d[4];
  if (is64) {
    i32x4 a = __builtin_nontemporal_load((const i32x4*)&ei[2 * (size_t)NE + 2 * (size_t)e0]);
    i32x4 b = __builtin_nontemporal_load((const i32x4*)&ei[2 * (size_t)NE + 2 * (size_t)e0 + 4]);
    d[0] = a[0]; d[1] = a[2]; d[2] = b[0]; d[3] = b[2];
  } else {
    i32x4 a = __builtin_nontemporal_load((const i32x4*)&ei[(size_t)NE + e0]);
    d[0] = a[0]; d[1] = a[1]; d[2] = a[2]; d[3] = a[3];
  }
  int lo = p * PSZ, hi = lo + PSZ;
  #pragma unroll
  for (int j = 0; j < 4; j++) {
    if (d[j] >= lo && d[j] < hi) {
      int s = is64 ? __builtin_nontemporal_load(&ei[2 * (size_t)(e0 + j)])
                   : __builtin_nontemporal_load(&ei[e0 + j]);
      int pos = atomicAdd(&cursor[d[j]], 1);
      recs[pos] = make_int2(s, __float_as_int(dis[s] * dis[d[j]]));
    }
  }
}

// ---------------- weight transpose + fp16 convert ----------------
__global__ void cvt_weights(const float* __restrict__ W1, const float* __restrict__ W2,
                            f16* __restrict__ W1t, f16* __restrict__ W2t) {
  int g = blockIdx.x * 256 + threadIdx.x;
  if (g < DIN * DHID) {
    int k = g >> 8, n = g & 255;
    W1t[(size_t)n * DIN + k] = (f16)W1[g];
  }
  if (g < DHID * DOUT) {
    int k = g >> 6, n = g & 63;
    W2t[(size_t)n * DHID + k] = (f16)W2[g];
  }
}

// ---------------- fused MLP via f16 MFMA (pipelined, union LDS) ----------
__global__ __launch_bounds__(256) void mlp_mfma(
    const float* __restrict__ x, const f16* __restrict__ W1t,
    const float* __restrict__ b1, const f16* __restrict__ W2t,
    const float* __restrict__ b2, const float* __restrict__ temp,
    f16* __restrict__ h, f16* __restrict__ z)
{
  __shared__ __align__(16) char smraw[2 * 64 * 136 * 2]; // 34816 B
  f16* xsb = (f16*)smraw;          // xs[buf][row][136]
  f16* h1s = (f16*)smraw;          // h1s[row][264] (aliases xs; disjoint lifetime)
  int t = threadIdx.x;
  int lane = t & 63;
  int w = t >> 6;
  int n0 = blockIdx.x * 64;
  int r15 = lane & 15;
  int g4 = lane >> 4;
  int nbase = w * 64;
  int srow = t >> 5, sc4 = t & 31;

  f32x4 acc[4][4];
  #pragma unroll
  for (int nt = 0; nt < 4; nt++) {
    float bv = b1[nbase + nt * 16 + r15];
    #pragma unroll
    for (int mt = 0; mt < 4; mt++) acc[mt][nt] = (f32x4){bv, bv, bv, bv};
  }

  float4 ld[8];
  #pragma unroll
  for (int it = 0; it < 8; it++) {
    int row = srow + it * 8;
    int gr = n0 + row;
    ld[it] = (gr < NN) ? *(const float4*)&x[(size_t)gr * DIN + sc4 * 4]
                       : make_float4(0.f, 0.f, 0.f, 0.f);
  }
  #pragma unroll
  for (int it = 0; it < 8; it++) {
    int row = srow + it * 8;
    f16x4 hv = { (f16)ld[it].x, (f16)ld[it].y, (f16)ld[it].z, (f16)ld[it].w };
    *(f16x4*)&xsb[row * 136 + sc4 * 4] = hv;
  }
  __syncthreads();

  for (int c = 0; c < 4; c++) {
    int cur = c & 1;
    if (c < 3) {
      #pragma unroll
      for (int it = 0; it < 8; it++) {
        int row = srow + it * 8;
        int gr = n0 + row;
        ld[it] = (gr < NN)
            ? *(const float4*)&x[(size_t)gr * DIN + (c + 1) * 128 + sc4 * 4]
            : make_float4(0.f, 0.f, 0.f, 0.f);
      }
    }
    int k0 = c * 128;
    const f16* xs = xsb + cur * 8704;
    #pragma unroll
    for (int ks = 0; ks < 4; ks++) {
      int kk = ks * 32 + g4 * 8;
      f16x8 a[4], b[4];
      #pragma unroll
      for (int mt = 0; mt < 4; mt++)
        a[mt] = *(const f16x8*)&xs[(mt * 16 + r15) * 136 + kk];
      #pragma unroll
      for (int nt = 0; nt < 4; nt++)
        b[nt] = *(const f16x8*)&W1t[(size_t)(nbase + nt * 16 + r15) * DIN + k0 + kk];
      #pragma unroll
      for (int mt = 0; mt < 4; mt++)
        #pragma unroll
        for (int nt = 0; nt < 4; nt++)
          acc[mt][nt] = __builtin_amdgcn_mfma_f32_16x16x32_f16(a[mt], b[nt], acc[mt][nt], 0, 0, 0);
    }
    if (c < 3) {
      #pragma unroll
      for (int it = 0; it < 8; it++) {
        int row = srow + it * 8;
        f16x4 hv = { (f16)ld[it].x, (f16)ld[it].y, (f16)ld[it].z, (f16)ld[it].w };
        *(f16x4*)&xsb[(cur ^ 1) * 8704 + row * 136 + sc4 * 4] = hv;
      }
    }
    __syncthreads();
  }

  #pragma unroll
  for (int mt = 0; mt < 4; mt++)
    #pragma unroll
    for (int nt = 0; nt < 4; nt++)
      #pragma unroll
      for (int r = 0; r < 4; r++) {
        float v = fmaxf(acc[mt][nt][r], 0.f);
        h1s[(mt * 16 + g4 * 4 + r) * 264 + nbase + nt * 16 + r15] = (f16)v;
      }
  __syncthreads();

  f32x4 acc2[4];
  #pragma unroll
  for (int nt = 0; nt < 4; nt++) {
    float bv = b2[nt * 16 + r15];
    acc2[nt] = (f32x4){bv, bv, bv, bv};
  }
  #pragma unroll
  for (int ks = 0; ks < 8; ks++) {
    int kk = ks * 32 + g4 * 8;
    f16x8 a2 = *(const f16x8*)&h1s[(w * 16 + r15) * 264 + kk];
    #pragma unroll
    for (int nt = 0; nt < 4; nt++) {
      f16x8 bf = *(const f16x8*)&W2t[(size_t)(nt * 16 + r15) * DHID + kk];
      acc2[nt] = __builtin_amdgcn_mfma_f32_16x16x32_f16(a2, bf, acc2[nt], 0, 0, 0);
    }
  }
  float tK = temp[KPROP];
  #pragma unroll
  for (int nt = 0; nt < 4; nt++)
    #pragma unroll
    for (int r = 0; r < 4; r++) {
      int node = n0 + w * 16 + g4 * 4 + r;
      if (node < NN) {
        int colv = nt * 16 + r15;
        float v = acc2[nt][r];
        h[(size_t)node * DOUT + colv] = (f16)v;
        z[(size_t)node * DOUT + colv] = (f16)(tK * v);
      }
    }
}

// ---------------- Horner propagation: z_new = temp[k]*h + A_hat z ----------
// r8 measured-best form (row-major z, 8 neighbor rows per dwordx4). r9's
// column-major slicing regressed 2x (FETCH 552MB/step: lost spatial locality,
// blockIdx can't sequence cache phases) — keep row-major.
__global__ __launch_bounds__(256) void prop_horner(
    const f16* __restrict__ z, f16* __restrict__ zn, const f16* __restrict__ h,
    float* __restrict__ out, const int* __restrict__ rs, const int* __restrict__ cnt,
    const int2* __restrict__ recs, const float* __restrict__ dis,
    const float* __restrict__ temp, int kidx, int final_step)
{
  int w = blockIdx.x * 4 + (threadIdx.x >> 6);
  int lane = threadIdx.x & 63;
  if (w >= NN) return;
  int q = lane >> 3;
  int s8 = lane & 7;

  float acc[8];
  #pragma unroll
  for (int f = 0; f < 8; f++) acc[f] = 0.f;

  int beg = rs[w], n = cnt[w];
  const int2* rp = recs + beg;

  int e = 0;
  for (; e + 32 <= n; e += 32) {
    int2 r0 = rp[e + q];
    int2 r1 = rp[e + 8 + q];
    int2 r2 = rp[e + 16 + q];
    int2 r3 = rp[e + 24 + q];
    f16x8 g0 = *(const f16x8*)&z[(size_t)r0.x * DOUT + s8 * 8];
    f16x8 g1 = *(const f16x8*)&z[(size_t)r1.x * DOUT + s8 * 8];
    f16x8 g2 = *(const f16x8*)&z[(size_t)r2.x * DOUT + s8 * 8];
    f16x8 g3 = *(const f16x8*)&z[(size_t)r3.x * DOUT + s8 * 8];
    float w0 = __int_as_float(r0.y);
    float w1 = __int_as_float(r1.y);
    float w2 = __int_as_float(r2.y);
    float w3 = __int_as_float(r3.y);
    #pragma unroll
    for (int f = 0; f < 8; f++) acc[f] = fmaf(w0, (float)g0[f], acc[f]);
    #pragma unroll
    for (int f = 0; f < 8; f++) acc[f] = fmaf(w1, (float)g1[f], acc[f]);
    #pragma unroll
    for (int f = 0; f < 8; f++) acc[f] = fmaf(w2, (float)g2[f], acc[f]);
    #pragma unroll
    for (int f = 0; f < 8; f++) acc[f] = fmaf(w3, (float)g3[f], acc[f]);
  }
  for (; e + 8 <= n; e += 8) {
    int2 r0 = rp[e + q];
    f16x8 g0 = *(const f16x8*)&z[(size_t)r0.x * DOUT + s8 * 8];
    float w0 = __int_as_float(r0.y);
    #pragma unroll
    for (int f = 0; f < 8; f++) acc[f] = fmaf(w0, (float)g0[f], acc[f]);
  }
  if (e < n) {
    int rem = n - e;
    int qq = q < rem ? q : rem - 1;   // clamp; invalid slots get weight 0
    int2 r0 = rp[e + qq];
    f16x8 g0 = *(const f16x8*)&z[(size_t)r0.x * DOUT + s8 * 8];
    float w0 = (q < rem) ? __int_as_float(r0.y) : 0.f;
    #pragma unroll
    for (int f = 0; f < 8; f++) acc[f] = fmaf(w0, (float)g0[f], acc[f]);
  }

  #pragma unroll
  for (int f = 0; f < 8; f++) {
    acc[f] += __shfl_xor(acc[f], 8);
    acc[f] += __shfl_xor(acc[f], 16);
    acc[f] += __shfl_xor(acc[f], 32);
  }

  if (q == 0) {
    float dd = dis[w];
    float dd2 = dd * dd;              // self-loop norm
    float gk = temp[kidx];
    f16x8 zs = *(const f16x8*)&z[(size_t)w * DOUT + s8 * 8];
    f16x8 hs = *(const f16x8*)&h[(size_t)w * DOUT + s8 * 8];
    #pragma unroll
    for (int f = 0; f < 8; f++)
      acc[f] += dd2 * (float)zs[f] + gk * (float)hs[f];
    if (final_step) {
      float4 o0 = { acc[0], acc[1], acc[2], acc[3] };
      float4 o1 = { acc[4], acc[5], acc[6], acc[7] };
      *(float4*)&out[(size_t)w * DOUT + s8 * 8] = o0;
      *(float4*)&out[(size_t)w * DOUT + s8 * 8 + 4] = o1;
    } else {
      f16x8 o;
      #pragma unroll
      for (int f = 0; f < 8; f++) o[f] = (f16)acc[f];
      *(f16x8*)&zn[(size_t)w * DOUT + s8 * 8] = o;
    }
  }
}

// ---------------- launch ----------------
extern "C" void kernel_launch(void* const* d_in, const int* in_sizes, int n_in,
                              void* d_out, int out_size, void* d_ws, size_t ws_size,
                              hipStream_t stream) {
  const float* x    = (const float*)d_in[0];
  const int*   ei   = (const int*)d_in[1];
  const float* W1   = (const float*)d_in[2];
  const float* b1   = (const float*)d_in[3];
  const float* W2   = (const float*)d_in[4];
  const float* b2   = (const float*)d_in[5];
  const float* temp = (const float*)d_in[6];
  float* out = (float*)d_out;

  char* wsb = (char*)d_ws;
  size_t off = 0;
  auto carve = [&](size_t bytes) -> void* {
    void* p = wsb + off;
    off = (off + bytes + 255) & ~(size_t)255;
    return p;
  };
  int*   cnt    = (int*)carve((size_t)NN * 4);
  int*   rs     = (int*)carve((size_t)NN * 4);
  int*   cursor = (int*)carve((size_t)NN * 4);
  int*   bsum   = (int*)carve(128 * 4);
  int*   flag   = (int*)carve(256);
  float* dis    = (float*)carve((size_t)NN * 4);
  int2*  recs   = (int2*)carve((size_t)NE * 8);  // 25.6 MB
  f16*   W1t    = (f16*)carve((size_t)DHID * DIN * 2);
  f16*   W2t    = (f16*)carve((size_t)DOUT * DHID * 2);
  f16*   h_buf  = (f16*)carve((size_t)NN * DOUT * 2);
  f16*   z_a    = (f16*)carve((size_t)NN * DOUT * 2);
  f16*   z_b    = (f16*)carve((size_t)NN * DOUT * 2);
  if (off > ws_size) return; // ~67 MB needed

  int nchunks = NE / 1024;  // 3125 (exact)

  detect_i64<<<1, 64, 0, stream>>>(ei, flag);
  zero_cnt<<<(NN + 255) / 256, 256, 0, stream>>>(cnt);
  count_deg<<<nchunks * NPART, 256, 0, stream>>>(ei, flag, cnt);
  scan1<<<(NN + 1023) / 1024, 1024, 0, stream>>>(cnt, rs, bsum);
  scan2<<<1, 64, 0, stream>>>(bsum, (NN + 1023) / 1024);
  scan3_and_dis<<<(NN + 255) / 256, 256, 0, stream>>>(rs, bsum, cursor, cnt, dis);
  fill_csr<<<nchunks * NPART, 256, 0, stream>>>(ei, flag, dis, cursor, recs);

  cvt_weights<<<(DIN * DHID + 255) / 256, 256, 0, stream>>>(W1, W2, W1t, W2t);
  mlp_mfma<<<(NN + 63) / 64, 256, 0, stream>>>(x, W1t, b1, W2t, b2, temp, h_buf, z_a);

  const f16* zc = z_a;
  f16* zn = z_b;
  for (int k = KPROP - 1; k >= 0; k--) {
    prop_horner<<<(NN + 3) / 4, 256, 0, stream>>>(zc, zn, h_buf, out, rs, cnt,
                                                  recs, dis, temp, k, k == 0);
    const f16* t2 = zn;
    zn = (f16*)zc;
    zc = t2;
  }
}

// Round 12
// 972.219 us; speedup vs baseline: 2.0579x; 1.1109x over previous
//
#include <hip/hip_runtime.h>

#define NN 100000
#define NE 3200000
#define DIN 512
#define DHID 256
#define DOUT 64
#define KPROP 10

typedef _Float16 f16;
typedef _Float16 f16x8 __attribute__((ext_vector_type(8)));
typedef _Float16 f16x4 __attribute__((ext_vector_type(4)));
typedef float f32x4 __attribute__((ext_vector_type(4)));

// ---------------- edge-index layout probe (wave-parallel) ----------------
__global__ void detect_i64(const int* __restrict__ ei, int* __restrict__ flag) {
  int lane = threadIdx.x;
  int ok = 1;
  for (int i = lane; i < 512; i += 64)
    if (ei[2 * i + 1] != 0) ok = 0;
  ok = __all(ok);
  if (lane == 0) *flag = ok;
}

__global__ void zero_cnt(int* __restrict__ cnt) {
  int g = blockIdx.x * blockDim.x + threadIdx.x;
  if (g < NN) cnt[g] = 0;
}

// ---------------- degree count + per-edge rank ----------------
// atomicAdd returns the edge's ordinal among its dst's edges — store it
// (coalesced int4). fill_csr then needs NO atomics: pos = rs[dst]+rank[e].
// (r11 lesson: fill's cost was the atomic->dependent-store latency chain,
// not write BW; routing and NT reads both falsified as write-amp fixes.)
__global__ void count_deg(const int* __restrict__ ei, const int* __restrict__ flag,
                          int* __restrict__ cnt, int* __restrict__ rank) {
  int g = blockIdx.x * blockDim.x + threadIdx.x;
  int e0 = g * 4;
  if (e0 >= NE) return;
  int is64 = *flag;
  int d0, d1, d2, d3;
  if (is64) {
    int4 a = *(const int4*)&ei[2 * (size_t)NE + 2 * (size_t)e0];
    int4 b = *(const int4*)&ei[2 * (size_t)NE + 2 * (size_t)e0 + 4];
    d0 = a.x; d1 = a.z; d2 = b.x; d3 = b.z;
  } else {
    int4 a = *(const int4*)&ei[(size_t)NE + e0];
    d0 = a.x; d1 = a.y; d2 = a.z; d3 = a.w;
  }
  int4 rk;
  rk.x = atomicAdd(&cnt[d0], 1);
  rk.y = atomicAdd(&cnt[d1], 1);
  rk.z = atomicAdd(&cnt[d2], 1);
  rk.w = atomicAdd(&cnt[d3], 1);
  *(int4*)&rank[e0] = rk;
}

// ---------------- exclusive scan over cnt ----------------
__global__ void scan1(const int* __restrict__ cnt, int* __restrict__ rs,
                      int* __restrict__ bsum) {
  __shared__ int tmp[1024];
  int t = threadIdx.x;
  int g = blockIdx.x * 1024 + t;
  int v = (g < NN) ? cnt[g] : 0;
  tmp[t] = v;
  __syncthreads();
  for (int off = 1; off < 1024; off <<= 1) {
    int y = (t >= off) ? tmp[t - off] : 0;
    __syncthreads();
    tmp[t] += y;
    __syncthreads();
  }
  if (g < NN) rs[g] = tmp[t] - v;           // exclusive
  if (t == 1023) bsum[blockIdx.x] = tmp[t]; // block total
}

__global__ void scan2(int* __restrict__ bsum, int nb) {
  if (blockIdx.x == 0 && threadIdx.x == 0) {
    int s = 0;
    for (int i = 0; i < nb; i++) { int v = bsum[i]; bsum[i] = s; s += v; }
  }
}

__global__ void scan3_and_dis(int* __restrict__ rs, const int* __restrict__ bsum,
                              const int* __restrict__ cnt, float* __restrict__ dis) {
  int g = blockIdx.x * blockDim.x + threadIdx.x;
  if (g < NN) {
    rs[g] = rs[g] + bsum[g >> 10];
    dis[g] = rsqrtf((float)(cnt[g] + 1)); // +1 self-loop
  }
}

// ---------------- CSR fill: atomic-free via precomputed ranks ----------
// Pure streaming reads + independent 8B scattered stores — full MLP, no
// dependent atomic->store chain.
__global__ void fill_csr(const int* __restrict__ ei, const int* __restrict__ flag,
                         const float* __restrict__ dis, const int* __restrict__ rs,
                         const int* __restrict__ rank, int2* __restrict__ recs) {
  int g = blockIdx.x * blockDim.x + threadIdx.x;
  int e0 = g * 4;
  if (e0 >= NE) return;
  int is64 = *flag;
  int s[4], d[4];
  if (is64) {
    int4 a = *(const int4*)&ei[2 * (size_t)NE + 2 * (size_t)e0];
    int4 b = *(const int4*)&ei[2 * (size_t)NE + 2 * (size_t)e0 + 4];
    d[0] = a.x; d[1] = a.z; d[2] = b.x; d[3] = b.z;
    int4 c = *(const int4*)&ei[2 * (size_t)e0];
    int4 e = *(const int4*)&ei[2 * (size_t)e0 + 4];
    s[0] = c.x; s[1] = c.z; s[2] = e.x; s[3] = e.z;
  } else {
    int4 a = *(const int4*)&ei[(size_t)NE + e0];
    d[0] = a.x; d[1] = a.y; d[2] = a.z; d[3] = a.w;
    int4 c = *(const int4*)&ei[e0];
    s[0] = c.x; s[1] = c.y; s[2] = c.z; s[3] = c.w;
  }
  int4 rk = *(const int4*)&rank[e0];
  int rka[4] = { rk.x, rk.y, rk.z, rk.w };
  #pragma unroll
  for (int j = 0; j < 4; j++) {
    int pos = rs[d[j]] + rka[j];
    recs[pos] = make_int2(s[j], __float_as_int(dis[s[j]] * dis[d[j]]));
  }
}

// ---------------- weight transpose + fp16 convert ----------------
__global__ void cvt_weights(const float* __restrict__ W1, const float* __restrict__ W2,
                            f16* __restrict__ W1t, f16* __restrict__ W2t) {
  int g = blockIdx.x * 256 + threadIdx.x;
  if (g < DIN * DHID) {
    int k = g >> 8, n = g & 255;
    W1t[(size_t)n * DIN + k] = (f16)W1[g];
  }
  if (g < DHID * DOUT) {
    int k = g >> 6, n = g & 63;
    W2t[(size_t)n * DHID + k] = (f16)W2[g];
  }
}

// ---------------- fused MLP via f16 MFMA (pipelined, union LDS) ----------
__global__ __launch_bounds__(256) void mlp_mfma(
    const float* __restrict__ x, const f16* __restrict__ W1t,
    const float* __restrict__ b1, const f16* __restrict__ W2t,
    const float* __restrict__ b2, const float* __restrict__ temp,
    f16* __restrict__ h, f16* __restrict__ z)
{
  __shared__ __align__(16) char smraw[2 * 64 * 136 * 2]; // 34816 B
  f16* xsb = (f16*)smraw;          // xs[buf][row][136]
  f16* h1s = (f16*)smraw;          // h1s[row][264] (aliases xs; disjoint lifetime)
  int t = threadIdx.x;
  int lane = t & 63;
  int w = t >> 6;
  int n0 = blockIdx.x * 64;
  int r15 = lane & 15;
  int g4 = lane >> 4;
  int nbase = w * 64;
  int srow = t >> 5, sc4 = t & 31;

  f32x4 acc[4][4];
  #pragma unroll
  for (int nt = 0; nt < 4; nt++) {
    float bv = b1[nbase + nt * 16 + r15];
    #pragma unroll
    for (int mt = 0; mt < 4; mt++) acc[mt][nt] = (f32x4){bv, bv, bv, bv};
  }

  float4 ld[8];
  #pragma unroll
  for (int it = 0; it < 8; it++) {
    int row = srow + it * 8;
    int gr = n0 + row;
    ld[it] = (gr < NN) ? *(const float4*)&x[(size_t)gr * DIN + sc4 * 4]
                       : make_float4(0.f, 0.f, 0.f, 0.f);
  }
  #pragma unroll
  for (int it = 0; it < 8; it++) {
    int row = srow + it * 8;
    f16x4 hv = { (f16)ld[it].x, (f16)ld[it].y, (f16)ld[it].z, (f16)ld[it].w };
    *(f16x4*)&xsb[row * 136 + sc4 * 4] = hv;
  }
  __syncthreads();

  for (int c = 0; c < 4; c++) {
    int cur = c & 1;
    if (c < 3) {
      #pragma unroll
      for (int it = 0; it < 8; it++) {
        int row = srow + it * 8;
        int gr = n0 + row;
        ld[it] = (gr < NN)
            ? *(const float4*)&x[(size_t)gr * DIN + (c + 1) * 128 + sc4 * 4]
            : make_float4(0.f, 0.f, 0.f, 0.f);
      }
    }
    int k0 = c * 128;
    const f16* xs = xsb + cur * 8704;
    #pragma unroll
    for (int ks = 0; ks < 4; ks++) {
      int kk = ks * 32 + g4 * 8;
      f16x8 a[4], b[4];
      #pragma unroll
      for (int mt = 0; mt < 4; mt++)
        a[mt] = *(const f16x8*)&xs[(mt * 16 + r15) * 136 + kk];
      #pragma unroll
      for (int nt = 0; nt < 4; nt++)
        b[nt] = *(const f16x8*)&W1t[(size_t)(nbase + nt * 16 + r15) * DIN + k0 + kk];
      #pragma unroll
      for (int mt = 0; mt < 4; mt++)
        #pragma unroll
        for (int nt = 0; nt < 4; nt++)
          acc[mt][nt] = __builtin_amdgcn_mfma_f32_16x16x32_f16(a[mt], b[nt], acc[mt][nt], 0, 0, 0);
    }
    if (c < 3) {
      #pragma unroll
      for (int it = 0; it < 8; it++) {
        int row = srow + it * 8;
        f16x4 hv = { (f16)ld[it].x, (f16)ld[it].y, (f16)ld[it].z, (f16)ld[it].w };
        *(f16x4*)&xsb[(cur ^ 1) * 8704 + row * 136 + sc4 * 4] = hv;
      }
    }
    __syncthreads();
  }

  #pragma unroll
  for (int mt = 0; mt < 4; mt++)
    #pragma unroll
    for (int nt = 0; nt < 4; nt++)
      #pragma unroll
      for (int r = 0; r < 4; r++) {
        float v = fmaxf(acc[mt][nt][r], 0.f);
        h1s[(mt * 16 + g4 * 4 + r) * 264 + nbase + nt * 16 + r15] = (f16)v;
      }
  __syncthreads();

  f32x4 acc2[4];
  #pragma unroll
  for (int nt = 0; nt < 4; nt++) {
    float bv = b2[nt * 16 + r15];
    acc2[nt] = (f32x4){bv, bv, bv, bv};
  }
  #pragma unroll
  for (int ks = 0; ks < 8; ks++) {
    int kk = ks * 32 + g4 * 8;
    f16x8 a2 = *(const f16x8*)&h1s[(w * 16 + r15) * 264 + kk];
    #pragma unroll
    for (int nt = 0; nt < 4; nt++) {
      f16x8 bf = *(const f16x8*)&W2t[(size_t)(nt * 16 + r15) * DHID + kk];
      acc2[nt] = __builtin_amdgcn_mfma_f32_16x16x32_f16(a2, bf, acc2[nt], 0, 0, 0);
    }
  }
  float tK = temp[KPROP];
  #pragma unroll
  for (int nt = 0; nt < 4; nt++)
    #pragma unroll
    for (int r = 0; r < 4; r++) {
      int node = n0 + w * 16 + g4 * 4 + r;
      if (node < NN) {
        int colv = nt * 16 + r15;
        float v = acc2[nt][r];
        h[(size_t)node * DOUT + colv] = (f16)v;
        z[(size_t)node * DOUT + colv] = (f16)(tK * v);
      }
    }
}

// ---------------- Horner propagation: z_new = temp[k]*h + A_hat z ----------
// r8 measured-best form (row-major z, 8 neighbor rows per dwordx4; q=lane>>3
// edge slot, s8=lane&7 feature octet; butterfly xor 8/16/32).
__global__ __launch_bounds__(256) void prop_horner(
    const f16* __restrict__ z, f16* __restrict__ zn, const f16* __restrict__ h,
    float* __restrict__ out, const int* __restrict__ rs, const int* __restrict__ cnt,
    const int2* __restrict__ recs, const float* __restrict__ dis,
    const float* __restrict__ temp, int kidx, int final_step)
{
  int w = blockIdx.x * 4 + (threadIdx.x >> 6);
  int lane = threadIdx.x & 63;
  if (w >= NN) return;
  int q = lane >> 3;
  int s8 = lane & 7;

  float acc[8];
  #pragma unroll
  for (int f = 0; f < 8; f++) acc[f] = 0.f;

  int beg = rs[w], n = cnt[w];
  const int2* rp = recs + beg;

  int e = 0;
  for (; e + 32 <= n; e += 32) {
    int2 r0 = rp[e + q];
    int2 r1 = rp[e + 8 + q];
    int2 r2 = rp[e + 16 + q];
    int2 r3 = rp[e + 24 + q];
    f16x8 g0 = *(const f16x8*)&z[(size_t)r0.x * DOUT + s8 * 8];
    f16x8 g1 = *(const f16x8*)&z[(size_t)r1.x * DOUT + s8 * 8];
    f16x8 g2 = *(const f16x8*)&z[(size_t)r2.x * DOUT + s8 * 8];
    f16x8 g3 = *(const f16x8*)&z[(size_t)r3.x * DOUT + s8 * 8];
    float w0 = __int_as_float(r0.y);
    float w1 = __int_as_float(r1.y);
    float w2 = __int_as_float(r2.y);
    float w3 = __int_as_float(r3.y);
    #pragma unroll
    for (int f = 0; f < 8; f++) acc[f] = fmaf(w0, (float)g0[f], acc[f]);
    #pragma unroll
    for (int f = 0; f < 8; f++) acc[f] = fmaf(w1, (float)g1[f], acc[f]);
    #pragma unroll
    for (int f = 0; f < 8; f++) acc[f] = fmaf(w2, (float)g2[f], acc[f]);
    #pragma unroll
    for (int f = 0; f < 8; f++) acc[f] = fmaf(w3, (float)g3[f], acc[f]);
  }
  for (; e + 8 <= n; e += 8) {
    int2 r0 = rp[e + q];
    f16x8 g0 = *(const f16x8*)&z[(size_t)r0.x * DOUT + s8 * 8];
    float w0 = __int_as_float(r0.y);
    #pragma unroll
    for (int f = 0; f < 8; f++) acc[f] = fmaf(w0, (float)g0[f], acc[f]);
  }
  if (e < n) {
    int rem = n - e;
    int qq = q < rem ? q : rem - 1;   // clamp; invalid slots get weight 0
    int2 r0 = rp[e + qq];
    f16x8 g0 = *(const f16x8*)&z[(size_t)r0.x * DOUT + s8 * 8];
    float w0 = (q < rem) ? __int_as_float(r0.y) : 0.f;
    #pragma unroll
    for (int f = 0; f < 8; f++) acc[f] = fmaf(w0, (float)g0[f], acc[f]);
  }

  #pragma unroll
  for (int f = 0; f < 8; f++) {
    acc[f] += __shfl_xor(acc[f], 8);
    acc[f] += __shfl_xor(acc[f], 16);
    acc[f] += __shfl_xor(acc[f], 32);
  }

  if (q == 0) {
    float dd = dis[w];
    float dd2 = dd * dd;              // self-loop norm
    float gk = temp[kidx];
    f16x8 zs = *(const f16x8*)&z[(size_t)w * DOUT + s8 * 8];
    f16x8 hs = *(const f16x8*)&h[(size_t)w * DOUT + s8 * 8];
    #pragma unroll
    for (int f = 0; f < 8; f++)
      acc[f] += dd2 * (float)zs[f] + gk * (float)hs[f];
    if (final_step) {
      float4 o0 = { acc[0], acc[1], acc[2], acc[3] };
      float4 o1 = { acc[4], acc[5], acc[6], acc[7] };
      *(float4*)&out[(size_t)w * DOUT + s8 * 8] = o0;
      *(float4*)&out[(size_t)w * DOUT + s8 * 8 + 4] = o1;
    } else {
      f16x8 o;
      #pragma unroll
      for (int f = 0; f < 8; f++) o[f] = (f16)acc[f];
      *(f16x8*)&zn[(size_t)w * DOUT + s8 * 8] = o;
    }
  }
}

// ---------------- launch ----------------
extern "C" void kernel_launch(void* const* d_in, const int* in_sizes, int n_in,
                              void* d_out, int out_size, void* d_ws, size_t ws_size,
                              hipStream_t stream) {
  const float* x    = (const float*)d_in[0];
  const int*   ei   = (const int*)d_in[1];
  const float* W1   = (const float*)d_in[2];
  const float* b1   = (const float*)d_in[3];
  const float* W2   = (const float*)d_in[4];
  const float* b2   = (const float*)d_in[5];
  const float* temp = (const float*)d_in[6];
  float* out = (float*)d_out;

  char* wsb = (char*)d_ws;
  size_t off = 0;
  auto carve = [&](size_t bytes) -> void* {
    void* p = wsb + off;
    off = (off + bytes + 255) & ~(size_t)255;
    return p;
  };
  int*   cnt    = (int*)carve((size_t)NN * 4);
  int*   rs     = (int*)carve((size_t)NN * 4);
  int*   bsum   = (int*)carve(128 * 4);
  int*   flag   = (int*)carve(256);
  float* dis    = (float*)carve((size_t)NN * 4);
  int*   rank   = (int*)carve((size_t)NE * 4);   // 12.8 MB
  int2*  recs   = (int2*)carve((size_t)NE * 8);  // 25.6 MB
  f16*   W1t    = (f16*)carve((size_t)DHID * DIN * 2);
  f16*   W2t    = (f16*)carve((size_t)DOUT * DHID * 2);
  f16*   h_buf  = (f16*)carve((size_t)NN * DOUT * 2);
  f16*   z_a    = (f16*)carve((size_t)NN * DOUT * 2);
  f16*   z_b    = (f16*)carve((size_t)NN * DOUT * 2);
  if (off > ws_size) return; // ~80 MB needed

  detect_i64<<<1, 64, 0, stream>>>(ei, flag);
  zero_cnt<<<(NN + 255) / 256, 256, 0, stream>>>(cnt);
  count_deg<<<(NE / 4 + 255) / 256, 256, 0, stream>>>(ei, flag, cnt, rank);
  scan1<<<(NN + 1023) / 1024, 1024, 0, stream>>>(cnt, rs, bsum);
  scan2<<<1, 64, 0, stream>>>(bsum, (NN + 1023) / 1024);
  scan3_and_dis<<<(NN + 255) / 256, 256, 0, stream>>>(rs, bsum, cnt, dis);
  fill_csr<<<(NE / 4 + 255) / 256, 256, 0, stream>>>(ei, flag, dis, rs, rank, recs);

  cvt_weights<<<(DIN * DHID + 255) / 256, 256, 0, stream>>>(W1, W2, W1t, W2t);
  mlp_mfma<<<(NN + 63) / 64, 256, 0, stream>>>(x, W1t, b1, W2t, b2, temp, h_buf, z_a);

  const f16* zc = z_a;
  f16* zn = z_b;
  for (int k = KPROP - 1; k >= 0; k--) {
    prop_horner<<<(NN + 3) / 4, 256, 0, stream>>>(zc, zn, h_buf, out, rs, cnt,
                                                  recs, dis, temp, k, k == 0);
    const f16* t2 = zn;
    zn = (f16*)zc;
    zc = t2;
  }
}